// Round 3
// baseline (815.882 us; speedup 1.0000x reference)
//
#include <hip/hip_runtime.h>

// Sparse MoE: T=4096 tokens, d=1024, E=8 experts, top-2, ffn=4096.
// route -> compact per-expert row lists (2T rows) -> bf16 MFMA grouped GEMM1
// (gelu) -> GEMM2 (scaled atomic scatter-add). Expert e pinned to XCD e via
// bid%8 swizzle (round-robin workgroup->XCD, m09) for L2 panel reuse.

#define TOKENS 4096
#define DMODEL 1024
#define NEXP   8
#define DFF    4096
#define NROWS  (2*TOKENS)

typedef __bf16 bf16_t;
typedef __bf16 bf16x8 __attribute__((ext_vector_type(8)));
typedef float  f32x4  __attribute__((ext_vector_type(4)));

__device__ __forceinline__ void gl_lds16(const void* g, void* l) {
    __builtin_amdgcn_global_load_lds(
        (const __attribute__((address_space(1))) void*)g,
        (__attribute__((address_space(3))) void*)l, 16, 0, 0);
}

// ---------------- router: logits, softmax, top-2, counts; also writes x->bf16 ----
__global__ __launch_bounds__(64) void router_k(
    const float* __restrict__ x, const float* __restrict__ rw,
    const float* __restrict__ rb, int* __restrict__ cnt,
    int* __restrict__ tok_e, int* __restrict__ tok_pos,
    float* __restrict__ tok_w, float* __restrict__ probs,
    bf16_t* __restrict__ xb)
{
    int t = blockIdx.x;
    int lane = threadIdx.x;
    const float* xr = x + (size_t)t * DMODEL;
    bf16_t* xbr = xb + (size_t)t * DMODEL;
    float s[NEXP];
#pragma unroll
    for (int e = 0; e < NEXP; e++) s[e] = 0.f;
    for (int i = lane; i < DMODEL; i += 64) {
        float xv = xr[i];
        xbr[i] = (bf16_t)xv;                 // fused fp32->bf16 convert of x
        const float* wr = rw + (size_t)i * NEXP;
#pragma unroll
        for (int e = 0; e < NEXP; e++) s[e] += xv * wr[e];
    }
#pragma unroll
    for (int e = 0; e < NEXP; e++) {
#pragma unroll
        for (int o = 32; o > 0; o >>= 1) s[e] += __shfl_down(s[e], o, 64);
    }
    if (lane == 0) {
        float mx = -1e30f;
#pragma unroll
        for (int e = 0; e < NEXP; e++) { s[e] += rb[e]; mx = fmaxf(mx, s[e]); }
        float den = 0.f;
#pragma unroll
        for (int e = 0; e < NEXP; e++) { s[e] = expf(s[e] - mx); den += s[e]; }
        float inv = 1.f / den;
#pragma unroll
        for (int e = 0; e < NEXP; e++) { s[e] *= inv; probs[t * NEXP + e] = s[e]; }
        int e0 = 0;
#pragma unroll
        for (int e = 1; e < NEXP; e++) if (s[e] > s[e0]) e0 = e;
        int e1 = (e0 == 0) ? 1 : 0;
#pragma unroll
        for (int e = 0; e < NEXP; e++) if (e != e0 && s[e] > s[e1]) e1 = e;
        float sw = s[e0] + s[e1];
        int p0 = atomicAdd(&cnt[e0], 1);
        int p1 = atomicAdd(&cnt[e1], 1);
        tok_e[2 * t] = e0;       tok_e[2 * t + 1] = e1;
        tok_pos[2 * t] = p0;     tok_pos[2 * t + 1] = p1;
        tok_w[2 * t] = s[e0] / sw; tok_w[2 * t + 1] = s[e1] / sw;
    }
}

__global__ void offsets_k(const int* __restrict__ cnt, int* __restrict__ off)
{
    if (threadIdx.x == 0) {
        int a = 0;
        for (int e = 0; e < NEXP; e++) { off[e] = a; a += cnt[e]; }
        off[NEXP] = a;
    }
}

__global__ void scatter_k(const int* __restrict__ tok_e, const int* __restrict__ tok_pos,
                          const float* __restrict__ tok_w, const int* __restrict__ off,
                          int* __restrict__ rows_tok, float* __restrict__ roww)
{
    int i = blockIdx.x * blockDim.x + threadIdx.x;
    if (i < 2 * TOKENS) {
        int e = tok_e[i];
        int g = off[e] + tok_pos[i];
        rows_tok[g] = i >> 1;
        roww[g] = tok_w[i];
    }
}

// ---------------- transpose+convert: [E][K][N] f32 -> [E][N][K] bf16 ----------------
// 64x64 tile. float4 global loads (16B/lane), bf16x8 global stores (16B/lane).
// TP=65 pad: both LDS phases land 2-way-per-bank (free, m136).
#define TP 65
__global__ __launch_bounds__(256) void transconv_k(const float* __restrict__ in,
                                                   bf16_t* __restrict__ o, int K, int N)
{
    __shared__ float t[64 * TP];
    int e = blockIdx.z;
    int n0 = blockIdx.x * 64, k0 = blockIdx.y * 64;
    int tid = threadIdx.x;
    int c4 = tid & 15, r = tid >> 4;
    const float* src = in + ((size_t)e * K + k0) * N + n0;
#pragma unroll
    for (int p = 0; p < 4; p++) {
        int k = r + p * 16;
        float4 v = *(const float4*)(src + (size_t)k * N + c4 * 4);
        float* d = &t[k * TP + c4 * 4];
        d[0] = v.x; d[1] = v.y; d[2] = v.z; d[3] = v.w;
    }
    __syncthreads();
    int k8 = tid & 7, n = tid >> 3;
    bf16_t* dst = o + ((size_t)e * N + n0) * K + k0;
#pragma unroll
    for (int p = 0; p < 2; p++) {
        int nn = n + p * 32;
        bf16x8 w;
#pragma unroll
        for (int j = 0; j < 8; j++) w[j] = (bf16_t)t[(k8 * 8 + j) * TP + nn];
        *(bf16x8*)(dst + (size_t)nn * K + k8 * 8) = w;
    }
}

// ---------------- grouped NT-GEMM, 128x128 tile, BK=64 ----------------
// MODE 0: h[row][:] = gelu(gather(x) @ w1 + b1)   (KDIM=1024, NT=32)
// MODE 1: out[tok][:] += w * (h @ w2 + b2)        (KDIM=4096, NT=8)
// 1-D grid, bid%8 = expert (XCD pin); same-XCD sequence sweeps y fast within x
// so the B-panel (128 cols) stays L2-resident.
template<int KDIM, int NT, int MODE>
__global__ __launch_bounds__(256) void ffn_gemm_k(
    const bf16_t* __restrict__ A, const bf16_t* __restrict__ Bt,
    const float* __restrict__ bias,
    const int* __restrict__ cnt, const int* __restrict__ off,
    const int* __restrict__ rows_tok, const float* __restrict__ roww,
    bf16_t* __restrict__ hbuf, float* __restrict__ out, int N)
{
    int bid = blockIdx.x;
    int e = bid & 7;
    int rest = bid >> 3;
    int yt = rest & 31;
    int xt = rest >> 5;
    int M = cnt[e];
    int m0 = yt * 128;
    if (m0 >= M) return;
    int n0 = xt * 128;
    int base = off[e];

    __shared__ __align__(16) bf16_t lA[128 * 64];
    __shared__ __align__(16) bf16_t lB[128 * 64];

    int tid = threadIdx.x;
    int wave = tid >> 6;
    int lane = tid & 63;
    // XOR swizzle: dst 16B-slot p of row r holds k-chunk p^(r&7).
    int sc = (lane & 7) ^ (lane >> 3);

    const bf16_t* aRow[4];
    const bf16_t* bRow[4];
#pragma unroll
    for (int i = 0; i < 4; i++) {
        int r = (wave * 4 + i) * 8 + (lane >> 3);
        int gr = m0 + r; if (gr > M - 1) gr = M - 1;
        if (MODE == 0) {
            int tok = rows_tok[base + gr];
            aRow[i] = A + (size_t)tok * KDIM;
        } else {
            aRow[i] = A + (size_t)(base + gr) * KDIM;
        }
        bRow[i] = Bt + ((size_t)e * N + n0 + r) * KDIM;
    }

    f32x4 acc[4][4];
    f32x4 zero = { 0.f, 0.f, 0.f, 0.f };
#pragma unroll
    for (int i = 0; i < 4; i++)
#pragma unroll
        for (int j = 0; j < 4; j++) acc[i][j] = zero;

    int wrow = wave >> 1, wcol = wave & 1;

#pragma unroll 1
    for (int kk = 0; kk < KDIM / 64; ++kk) {
        int koff = kk * 64 + sc * 8;
#pragma unroll
        for (int i = 0; i < 4; i++) {
            gl_lds16(aRow[i] + koff, &lA[(wave * 4 + i) * 512]);
            gl_lds16(bRow[i] + koff, &lB[(wave * 4 + i) * 512]);
        }
        __syncthreads();
#pragma unroll
        for (int ks = 0; ks < 2; ++ks) {
            bf16x8 af[4], bfr[4];
#pragma unroll
            for (int mt = 0; mt < 4; mt++) {
                int r = wrow * 64 + mt * 16 + (lane & 15);
                int ch = (ks * 4 + (lane >> 4)) ^ (r & 7);
                af[mt] = *(const bf16x8*)&lA[r * 64 + ch * 8];
            }
#pragma unroll
            for (int nt = 0; nt < 4; nt++) {
                int c = wcol * 64 + nt * 16 + (lane & 15);
                int ch = (ks * 4 + (lane >> 4)) ^ (c & 7);
                bfr[nt] = *(const bf16x8*)&lB[c * 64 + ch * 8];
            }
#pragma unroll
            for (int mt = 0; mt < 4; mt++)
#pragma unroll
                for (int nt = 0; nt < 4; nt++)
                    acc[mt][nt] = __builtin_amdgcn_mfma_f32_16x16x32_bf16(
                        af[mt], bfr[nt], acc[mt][nt], 0, 0, 0);
        }
        __syncthreads();
    }

    // epilogue. C/D map: col = lane&15, row = (lane>>4)*4 + reg  [m89/m91]
    float bv[4];
#pragma unroll
    for (int nt = 0; nt < 4; nt++)
        bv[nt] = bias[(size_t)e * N + n0 + wcol * 64 + nt * 16 + (lane & 15)];

#pragma unroll
    for (int mt = 0; mt < 4; mt++) {
#pragma unroll
        for (int q = 0; q < 4; q++) {
            int r = wrow * 64 + mt * 16 + (lane >> 4) * 4 + q;
            int gm = m0 + r;
            if (gm < M) {
                if (MODE == 0) {
                    size_t hrow = (size_t)(base + gm) * DFF;
#pragma unroll
                    for (int nt = 0; nt < 4; nt++) {
                        float v = acc[mt][nt][q] + bv[nt];
                        v = 0.5f * v * (1.f + erff(v * 0.70710678118654752f));
                        int c = n0 + wcol * 64 + nt * 16 + (lane & 15);
                        hbuf[hrow + c] = (bf16_t)v;
                    }
                } else {
                    int g = base + gm;
                    int tok = rows_tok[g];
                    float wgt = roww[g];
                    size_t orow = (size_t)tok * DMODEL;
#pragma unroll
                    for (int nt = 0; nt < 4; nt++) {
                        float v = acc[mt][nt][q] + bv[nt];
                        int c = n0 + wcol * 64 + nt * 16 + (lane & 15);
                        atomicAdd(&out[orow + c], wgt * v);
                    }
                }
            }
        }
    }
}

// ---------------- aux loss: var(mean_probs, ddof=1) ----------------
__global__ __launch_bounds__(256) void aux_k(const float* __restrict__ probs,
                                             float* __restrict__ out_aux)
{
    __shared__ float red[256];
    __shared__ float mexp[NEXP];
    float s[NEXP];
#pragma unroll
    for (int e = 0; e < NEXP; e++) s[e] = 0.f;
    for (int t = threadIdx.x; t < TOKENS; t += 256) {
#pragma unroll
        for (int e = 0; e < NEXP; e++) s[e] += probs[t * NEXP + e];
    }
    for (int e = 0; e < NEXP; e++) {
        red[threadIdx.x] = s[e];
        __syncthreads();
        for (int st = 128; st > 0; st >>= 1) {
            if (threadIdx.x < st) red[threadIdx.x] += red[threadIdx.x + st];
            __syncthreads();
        }
        if (threadIdx.x == 0) mexp[e] = red[0] / (float)TOKENS;
        __syncthreads();
    }
    if (threadIdx.x == 0) {
        float mean = 0.f;
        for (int e = 0; e < NEXP; e++) mean += mexp[e];
        mean /= (float)NEXP;
        float v = 0.f;
        for (int e = 0; e < NEXP; e++) { float d = mexp[e] - mean; v += d * d; }
        out_aux[0] = v / (float)(NEXP - 1);
    }
}

extern "C" void kernel_launch(void* const* d_in, const int* in_sizes, int n_in,
                              void* d_out, int out_size, void* d_ws, size_t ws_size,
                              hipStream_t stream)
{
    const float* x  = (const float*)d_in[0];
    const float* rw = (const float*)d_in[1];
    const float* rb = (const float*)d_in[2];
    const float* w1 = (const float*)d_in[3];
    const float* b1 = (const float*)d_in[4];
    const float* w2 = (const float*)d_in[5];
    const float* b2 = (const float*)d_in[6];
    float* out = (float*)d_out;

    char* p = (char*)d_ws;
    auto alloc = [&](size_t b) { char* q = p; p += (b + 255) & ~(size_t)255; return q; };
    int*    cnt      = (int*)   alloc(NEXP * sizeof(int));
    int*    off      = (int*)   alloc((NEXP + 1) * sizeof(int));
    int*    tok_e    = (int*)   alloc(2 * TOKENS * sizeof(int));
    int*    tok_pos  = (int*)   alloc(2 * TOKENS * sizeof(int));
    float*  tok_w    = (float*) alloc(2 * TOKENS * sizeof(float));
    int*    rows_tok = (int*)   alloc(NROWS * sizeof(int));
    float*  roww     = (float*) alloc(NROWS * sizeof(float));
    float*  probs    = (float*) alloc((size_t)TOKENS * NEXP * sizeof(float));
    bf16_t* xb       = (bf16_t*)alloc((size_t)TOKENS * DMODEL * 2);
    bf16_t* w1t      = (bf16_t*)alloc((size_t)NEXP * DFF * DMODEL * 2);
    bf16_t* w2t      = (bf16_t*)alloc((size_t)NEXP * DMODEL * DFF * 2);
    bf16_t* hbuf     = (bf16_t*)alloc((size_t)NROWS * DFF * 2);

    hipMemsetAsync(cnt, 0, NEXP * sizeof(int), stream);
    hipMemsetAsync(d_out, 0, (size_t)out_size * sizeof(float), stream);

    router_k<<<TOKENS, 64, 0, stream>>>(x, rw, rb, cnt, tok_e, tok_pos, tok_w, probs, xb);
    offsets_k<<<1, 64, 0, stream>>>(cnt, off);
    scatter_k<<<(2 * TOKENS + 255) / 256, 256, 0, stream>>>(tok_e, tok_pos, tok_w, off,
                                                            rows_tok, roww);
    transconv_k<<<dim3(DFF / 64, DMODEL / 64, NEXP), 256, 0, stream>>>(w1, w1t, DMODEL, DFF);
    transconv_k<<<dim3(DMODEL / 64, DFF / 64, NEXP), 256, 0, stream>>>(w2, w2t, DFF, DMODEL);

    ffn_gemm_k<DMODEL, 32, 0><<<NEXP * 32 * 32, 256, 0, stream>>>(
        xb, w1t, b1, cnt, off, rows_tok, roww, hbuf, out, DFF);
    ffn_gemm_k<DFF, 8, 1><<<NEXP * 32 * 8, 256, 0, stream>>>(
        hbuf, w2t, b2, cnt, off, rows_tok, roww, hbuf, out, DMODEL);

    aux_k<<<1, 256, 0, stream>>>(probs, out + (size_t)TOKENS * DMODEL);
}

// Round 4
// 661.986 us; speedup vs baseline: 1.2325x; 1.2325x over previous
//
#include <hip/hip_runtime.h>

// Sparse MoE: T=4096 tokens, d=1024, E=8 experts, top-2, ffn=4096.
// route -> compact per-expert row lists (2T rows) -> bf16 MFMA grouped GEMM1
// (gelu) -> GEMM2 split-K=4 (deterministic bf16 partials, no atomics) ->
// combine (token-major weighted sum + bias). Expert e pinned to XCD e via
// bid&7 (round-robin workgroup->XCD, m09): per-expert A slab stays L2-resident
// (verified: GEMM1 FETCH 65 MB ~= unique bytes, round 3).

#define TOKENS 4096
#define DMODEL 1024
#define NEXP   8
#define DFF    4096
#define NROWS  (2*TOKENS)
#define SPLITK 4

typedef __bf16 bf16_t;
typedef __bf16 bf16x8 __attribute__((ext_vector_type(8)));
typedef __bf16 bf16x4 __attribute__((ext_vector_type(4)));
typedef float  f32x4  __attribute__((ext_vector_type(4)));

__device__ __forceinline__ void gl_lds16(const void* g, void* l) {
    __builtin_amdgcn_global_load_lds(
        (const __attribute__((address_space(1))) void*)g,
        (__attribute__((address_space(3))) void*)l, 16, 0, 0);
}

// ---------------- router: logits, softmax, top-2, counts; also writes x->bf16 ----
__global__ __launch_bounds__(64) void router_k(
    const float* __restrict__ x, const float* __restrict__ rw,
    const float* __restrict__ rb, int* __restrict__ cnt,
    int* __restrict__ tok_e, int* __restrict__ tok_pos,
    float* __restrict__ tok_w, float* __restrict__ probs,
    bf16_t* __restrict__ xb)
{
    int t = blockIdx.x;
    int lane = threadIdx.x;
    const float* xr = x + (size_t)t * DMODEL;
    bf16_t* xbr = xb + (size_t)t * DMODEL;
    float s[NEXP];
#pragma unroll
    for (int e = 0; e < NEXP; e++) s[e] = 0.f;
    for (int i = lane; i < DMODEL; i += 64) {
        float xv = xr[i];
        xbr[i] = (bf16_t)xv;                 // fused fp32->bf16 convert of x
        const float* wr = rw + (size_t)i * NEXP;
#pragma unroll
        for (int e = 0; e < NEXP; e++) s[e] += xv * wr[e];
    }
#pragma unroll
    for (int e = 0; e < NEXP; e++) {
#pragma unroll
        for (int o = 32; o > 0; o >>= 1) s[e] += __shfl_down(s[e], o, 64);
    }
    if (lane == 0) {
        float mx = -1e30f;
#pragma unroll
        for (int e = 0; e < NEXP; e++) { s[e] += rb[e]; mx = fmaxf(mx, s[e]); }
        float den = 0.f;
#pragma unroll
        for (int e = 0; e < NEXP; e++) { s[e] = expf(s[e] - mx); den += s[e]; }
        float inv = 1.f / den;
#pragma unroll
        for (int e = 0; e < NEXP; e++) { s[e] *= inv; probs[t * NEXP + e] = s[e]; }
        int e0 = 0;
#pragma unroll
        for (int e = 1; e < NEXP; e++) if (s[e] > s[e0]) e0 = e;
        int e1 = (e0 == 0) ? 1 : 0;
#pragma unroll
        for (int e = 0; e < NEXP; e++) if (e != e0 && s[e] > s[e1]) e1 = e;
        float sw = s[e0] + s[e1];
        int p0 = atomicAdd(&cnt[e0], 1);
        int p1 = atomicAdd(&cnt[e1], 1);
        tok_e[2 * t] = e0;       tok_e[2 * t + 1] = e1;
        tok_pos[2 * t] = p0;     tok_pos[2 * t + 1] = p1;
        tok_w[2 * t] = s[e0] / sw; tok_w[2 * t + 1] = s[e1] / sw;
    }
}

__global__ void offsets_k(const int* __restrict__ cnt, int* __restrict__ off)
{
    if (threadIdx.x == 0) {
        int a = 0;
        for (int e = 0; e < NEXP; e++) { off[e] = a; a += cnt[e]; }
        off[NEXP] = a;
    }
}

__global__ void scatter_k(const int* __restrict__ tok_e, const int* __restrict__ tok_pos,
                          const float* __restrict__ tok_w, const int* __restrict__ off,
                          int* __restrict__ rows_tok, float* __restrict__ roww,
                          int* __restrict__ g_of)
{
    int i = blockIdx.x * blockDim.x + threadIdx.x;
    if (i < 2 * TOKENS) {
        int e = tok_e[i];
        int g = off[e] + tok_pos[i];
        rows_tok[g] = i >> 1;
        roww[g] = tok_w[i];
        g_of[i] = g;             // token slot -> compact row (for combine)
    }
}

// ---------------- transpose+convert: [E][K][N] f32 -> [E][N][K] bf16 ----------------
// 64x64 tile. float4 global loads (16B/lane), bf16x8 global stores (16B/lane).
// TP=65 pad: both LDS phases land 2-way-per-bank (free, m136).
#define TP 65
__global__ __launch_bounds__(256) void transconv_k(const float* __restrict__ in,
                                                   bf16_t* __restrict__ o, int K, int N)
{
    __shared__ float t[64 * TP];
    int e = blockIdx.z;
    int n0 = blockIdx.x * 64, k0 = blockIdx.y * 64;
    int tid = threadIdx.x;
    int c4 = tid & 15, r = tid >> 4;
    const float* src = in + ((size_t)e * K + k0) * N + n0;
#pragma unroll
    for (int p = 0; p < 4; p++) {
        int k = r + p * 16;
        float4 v = *(const float4*)(src + (size_t)k * N + c4 * 4);
        float* d = &t[k * TP + c4 * 4];
        d[0] = v.x; d[1] = v.y; d[2] = v.z; d[3] = v.w;
    }
    __syncthreads();
    int k8 = tid & 7, n = tid >> 3;
    bf16_t* dst = o + ((size_t)e * N + n0) * K + k0;
#pragma unroll
    for (int p = 0; p < 2; p++) {
        int nn = n + p * 32;
        bf16x8 w;
#pragma unroll
        for (int j = 0; j < 8; j++) w[j] = (bf16_t)t[(k8 * 8 + j) * TP + nn];
        *(bf16x8*)(dst + (size_t)nn * K + k8 * 8) = w;
    }
}

// ---------------- GEMM1: h = gelu(gather(x) @ w1 + b1), 128x128 tile, BK=64 ----
// grid: bid&7 = expert (XCD pin); rest: yt fastest (A 2MB/expert L2-resident,
// B panels stream once -> FETCH ~= unique, verified round 3).
__global__ __launch_bounds__(256, 2) void gemm1_k(
    const bf16_t* __restrict__ A, const bf16_t* __restrict__ Bt,
    const float* __restrict__ bias,
    const int* __restrict__ cnt, const int* __restrict__ off,
    const int* __restrict__ rows_tok, bf16_t* __restrict__ hbuf)
{
    int bid = blockIdx.x;
    int e = bid & 7;
    int rest = bid >> 3;
    int yt = rest & 31;
    int xt = rest >> 5;
    int M = cnt[e];
    int m0 = yt * 128;
    if (m0 >= M) return;
    int n0 = xt * 128;
    int base = off[e];

    __shared__ __align__(16) bf16_t lA[128 * 64];
    __shared__ __align__(16) bf16_t lB[128 * 64];

    int tid = threadIdx.x;
    int wave = tid >> 6;
    int lane = tid & 63;
    int sc = (lane & 7) ^ (lane >> 3);   // XOR swizzle: slot p of row r holds chunk p^(r&7)

    const bf16_t* aRow[4];
    const bf16_t* bRow[4];
#pragma unroll
    for (int i = 0; i < 4; i++) {
        int r = (wave * 4 + i) * 8 + (lane >> 3);
        int gr = m0 + r; if (gr > M - 1) gr = M - 1;
        int tok = rows_tok[base + gr];
        aRow[i] = A + (size_t)tok * DMODEL;
        bRow[i] = Bt + ((size_t)e * DFF + n0 + r) * DMODEL;
    }

    f32x4 acc[4][4];
    f32x4 zero = { 0.f, 0.f, 0.f, 0.f };
#pragma unroll
    for (int i = 0; i < 4; i++)
#pragma unroll
        for (int j = 0; j < 4; j++) acc[i][j] = zero;

    int wrow = wave >> 1, wcol = wave & 1;

#pragma unroll 1
    for (int kk = 0; kk < DMODEL / 64; ++kk) {
        int koff = kk * 64 + sc * 8;
#pragma unroll
        for (int i = 0; i < 4; i++) {
            gl_lds16(aRow[i] + koff, &lA[(wave * 4 + i) * 512]);
            gl_lds16(bRow[i] + koff, &lB[(wave * 4 + i) * 512]);
        }
        __syncthreads();
#pragma unroll
        for (int ks = 0; ks < 2; ++ks) {
            bf16x8 af[4], bfr[4];
#pragma unroll
            for (int mt = 0; mt < 4; mt++) {
                int r = wrow * 64 + mt * 16 + (lane & 15);
                int ch = (ks * 4 + (lane >> 4)) ^ (r & 7);
                af[mt] = *(const bf16x8*)&lA[r * 64 + ch * 8];
            }
#pragma unroll
            for (int nt = 0; nt < 4; nt++) {
                int c = wcol * 64 + nt * 16 + (lane & 15);
                int ch = (ks * 4 + (lane >> 4)) ^ (c & 7);
                bfr[nt] = *(const bf16x8*)&lB[c * 64 + ch * 8];
            }
#pragma unroll
            for (int mt = 0; mt < 4; mt++)
#pragma unroll
                for (int nt = 0; nt < 4; nt++)
                    acc[mt][nt] = __builtin_amdgcn_mfma_f32_16x16x32_bf16(
                        af[mt], bfr[nt], acc[mt][nt], 0, 0, 0);
        }
        __syncthreads();
    }

    // C/D map: col = lane&15, row = (lane>>4)*4 + reg  [m89/m91]
    float bv[4];
#pragma unroll
    for (int nt = 0; nt < 4; nt++)
        bv[nt] = bias[(size_t)e * DFF + n0 + wcol * 64 + nt * 16 + (lane & 15)];

#pragma unroll
    for (int mt = 0; mt < 4; mt++) {
#pragma unroll
        for (int q = 0; q < 4; q++) {
            int r = wrow * 64 + mt * 16 + (lane >> 4) * 4 + q;
            int gm = m0 + r;
            if (gm < M) {
                size_t hrow = (size_t)(base + gm) * DFF;
#pragma unroll
                for (int nt = 0; nt < 4; nt++) {
                    float v = acc[mt][nt][q] + bv[nt];
                    v = 0.5f * v * (1.f + erff(v * 0.70710678118654752f));
                    int c = n0 + wcol * 64 + nt * 16 + (lane & 15);
                    hbuf[hrow + c] = (bf16_t)v;
                }
            }
        }
    }
}

// ---------------- GEMM2: split-K=4 partials, no bias/weight, no atomics ----
// ybuf[kt][g][c] = (h[g][kt-quarter] @ w2[kt-quarter][c]) as bf16.
// grid: bid&7 = expert; rest: yt fastest, then xt, kt slowest -> per-kt A
// quarter-slab (2 MB/expert) L2-resident, B panels stream once.
__global__ __launch_bounds__(256, 2) void gemm2_k(
    const bf16_t* __restrict__ A, const bf16_t* __restrict__ Bt,
    const int* __restrict__ cnt, const int* __restrict__ off,
    bf16_t* __restrict__ ybuf)
{
    int bid = blockIdx.x;
    int e = bid & 7;
    int rest = bid >> 3;
    int yt = rest & 31;
    int xt = (rest >> 5) & 7;
    int kt = rest >> 8;
    int M = cnt[e];
    int m0 = yt * 128;
    if (m0 >= M) return;
    int n0 = xt * 128;
    int base = off[e];
    int k0 = kt * (DFF / SPLITK);

    __shared__ __align__(16) bf16_t lA[128 * 64];
    __shared__ __align__(16) bf16_t lB[128 * 64];

    int tid = threadIdx.x;
    int wave = tid >> 6;
    int lane = tid & 63;
    int sc = (lane & 7) ^ (lane >> 3);

    const bf16_t* aRow[4];
    const bf16_t* bRow[4];
#pragma unroll
    for (int i = 0; i < 4; i++) {
        int r = (wave * 4 + i) * 8 + (lane >> 3);
        int gr = m0 + r; if (gr > M - 1) gr = M - 1;
        aRow[i] = A + (size_t)(base + gr) * DFF + k0;
        bRow[i] = Bt + ((size_t)e * DMODEL + n0 + r) * DFF + k0;
    }

    f32x4 acc[4][4];
    f32x4 zero = { 0.f, 0.f, 0.f, 0.f };
#pragma unroll
    for (int i = 0; i < 4; i++)
#pragma unroll
        for (int j = 0; j < 4; j++) acc[i][j] = zero;

    int wrow = wave >> 1, wcol = wave & 1;

#pragma unroll 1
    for (int kk = 0; kk < (DFF / SPLITK) / 64; ++kk) {
        int koff = kk * 64 + sc * 8;
#pragma unroll
        for (int i = 0; i < 4; i++) {
            gl_lds16(aRow[i] + koff, &lA[(wave * 4 + i) * 512]);
            gl_lds16(bRow[i] + koff, &lB[(wave * 4 + i) * 512]);
        }
        __syncthreads();
#pragma unroll
        for (int ks = 0; ks < 2; ++ks) {
            bf16x8 af[4], bfr[4];
#pragma unroll
            for (int mt = 0; mt < 4; mt++) {
                int r = wrow * 64 + mt * 16 + (lane & 15);
                int ch = (ks * 4 + (lane >> 4)) ^ (r & 7);
                af[mt] = *(const bf16x8*)&lA[r * 64 + ch * 8];
            }
#pragma unroll
            for (int nt = 0; nt < 4; nt++) {
                int c = wcol * 64 + nt * 16 + (lane & 15);
                int ch = (ks * 4 + (lane >> 4)) ^ (c & 7);
                bfr[nt] = *(const bf16x8*)&lB[c * 64 + ch * 8];
            }
#pragma unroll
            for (int mt = 0; mt < 4; mt++)
#pragma unroll
                for (int nt = 0; nt < 4; nt++)
                    acc[mt][nt] = __builtin_amdgcn_mfma_f32_16x16x32_bf16(
                        af[mt], bfr[nt], acc[mt][nt], 0, 0, 0);
        }
        __syncthreads();
    }

#pragma unroll
    for (int mt = 0; mt < 4; mt++) {
#pragma unroll
        for (int q = 0; q < 4; q++) {
            int r = wrow * 64 + mt * 16 + (lane >> 4) * 4 + q;
            int gm = m0 + r;
            if (gm < M) {
                size_t yrow = ((size_t)kt * NROWS + base + gm) * DMODEL;
#pragma unroll
                for (int nt = 0; nt < 4; nt++) {
                    int c = n0 + wcol * 64 + nt * 16 + (lane & 15);
                    ybuf[yrow + c] = (bf16_t)acc[mt][nt][q];
                }
            }
        }
    }
}

// ---------------- combine: out[t] = sum_k(w0*(y[g0]+b2[e0]) + w1*(y[g1]+b2[e1])) ----
__global__ __launch_bounds__(256) void combine_k(
    const bf16_t* __restrict__ ybuf, const int* __restrict__ g_of,
    const int* __restrict__ tok_e, const float* __restrict__ tok_w,
    const float* __restrict__ b2, float* __restrict__ out)
{
    int t = blockIdx.x;
    int c = threadIdx.x * 4;
    int g0 = g_of[2 * t], g1 = g_of[2 * t + 1];
    int e0 = tok_e[2 * t], e1 = tok_e[2 * t + 1];
    float w0 = tok_w[2 * t], w1 = tok_w[2 * t + 1];
    float a0[4] = {0.f, 0.f, 0.f, 0.f}, a1[4] = {0.f, 0.f, 0.f, 0.f};
#pragma unroll
    for (int kt = 0; kt < SPLITK; kt++) {
        bf16x4 y0 = *(const bf16x4*)&ybuf[((size_t)kt * NROWS + g0) * DMODEL + c];
        bf16x4 y1 = *(const bf16x4*)&ybuf[((size_t)kt * NROWS + g1) * DMODEL + c];
#pragma unroll
        for (int j = 0; j < 4; j++) { a0[j] += (float)y0[j]; a1[j] += (float)y1[j]; }
    }
    float4 bb0 = *(const float4*)&b2[(size_t)e0 * DMODEL + c];
    float4 bb1 = *(const float4*)&b2[(size_t)e1 * DMODEL + c];
    float4 r;
    r.x = w0 * (a0[0] + bb0.x) + w1 * (a1[0] + bb1.x);
    r.y = w0 * (a0[1] + bb0.y) + w1 * (a1[1] + bb1.y);
    r.z = w0 * (a0[2] + bb0.z) + w1 * (a1[2] + bb1.z);
    r.w = w0 * (a0[3] + bb0.w) + w1 * (a1[3] + bb1.w);
    *(float4*)&out[(size_t)t * DMODEL + c] = r;
}

// ---------------- aux loss: var(mean_probs, ddof=1) ----------------
__global__ __launch_bounds__(256) void aux_k(const float* __restrict__ probs,
                                             float* __restrict__ out_aux)
{
    __shared__ float red[256];
    __shared__ float mexp[NEXP];
    float s[NEXP];
#pragma unroll
    for (int e = 0; e < NEXP; e++) s[e] = 0.f;
    for (int t = threadIdx.x; t < TOKENS; t += 256) {
#pragma unroll
        for (int e = 0; e < NEXP; e++) s[e] += probs[t * NEXP + e];
    }
    for (int e = 0; e < NEXP; e++) {
        red[threadIdx.x] = s[e];
        __syncthreads();
        for (int st = 128; st > 0; st >>= 1) {
            if (threadIdx.x < st) red[threadIdx.x] += red[threadIdx.x + st];
            __syncthreads();
        }
        if (threadIdx.x == 0) mexp[e] = red[0] / (float)TOKENS;
        __syncthreads();
    }
    if (threadIdx.x == 0) {
        float mean = 0.f;
        for (int e = 0; e < NEXP; e++) mean += mexp[e];
        mean /= (float)NEXP;
        float v = 0.f;
        for (int e = 0; e < NEXP; e++) { float d = mexp[e] - mean; v += d * d; }
        out_aux[0] = v / (float)(NEXP - 1);
    }
}

extern "C" void kernel_launch(void* const* d_in, const int* in_sizes, int n_in,
                              void* d_out, int out_size, void* d_ws, size_t ws_size,
                              hipStream_t stream)
{
    const float* x  = (const float*)d_in[0];
    const float* rw = (const float*)d_in[1];
    const float* rb = (const float*)d_in[2];
    const float* w1 = (const float*)d_in[3];
    const float* b1 = (const float*)d_in[4];
    const float* w2 = (const float*)d_in[5];
    const float* b2 = (const float*)d_in[6];
    float* out = (float*)d_out;

    char* p = (char*)d_ws;
    auto alloc = [&](size_t b) { char* q = p; p += (b + 255) & ~(size_t)255; return q; };
    int*    cnt      = (int*)   alloc(NEXP * sizeof(int));
    int*    off      = (int*)   alloc((NEXP + 1) * sizeof(int));
    int*    tok_e    = (int*)   alloc(2 * TOKENS * sizeof(int));
    int*    tok_pos  = (int*)   alloc(2 * TOKENS * sizeof(int));
    float*  tok_w    = (float*) alloc(2 * TOKENS * sizeof(float));
    int*    rows_tok = (int*)   alloc(NROWS * sizeof(int));
    float*  roww     = (float*) alloc(NROWS * sizeof(float));
    int*    g_of     = (int*)   alloc(2 * TOKENS * sizeof(int));
    float*  probs    = (float*) alloc((size_t)TOKENS * NEXP * sizeof(float));
    bf16_t* xb       = (bf16_t*)alloc((size_t)TOKENS * DMODEL * 2);
    bf16_t* w1t      = (bf16_t*)alloc((size_t)NEXP * DFF * DMODEL * 2);
    bf16_t* w2t      = (bf16_t*)alloc((size_t)NEXP * DMODEL * DFF * 2);
    bf16_t* hbuf     = (bf16_t*)alloc((size_t)NROWS * DFF * 2);
    // ybuf (split-K partials, 64 MB) aliases w1t: w1t is dead once gemm1 completes,
    // gemm2 runs strictly after on the same stream.
    bf16_t* ybuf     = w1t;

    hipMemsetAsync(cnt, 0, NEXP * sizeof(int), stream);

    router_k<<<TOKENS, 64, 0, stream>>>(x, rw, rb, cnt, tok_e, tok_pos, tok_w, probs, xb);
    offsets_k<<<1, 64, 0, stream>>>(cnt, off);
    scatter_k<<<(2 * TOKENS + 255) / 256, 256, 0, stream>>>(tok_e, tok_pos, tok_w, off,
                                                            rows_tok, roww, g_of);
    transconv_k<<<dim3(DFF / 64, DMODEL / 64, NEXP), 256, 0, stream>>>(w1, w1t, DMODEL, DFF);
    transconv_k<<<dim3(DMODEL / 64, DFF / 64, NEXP), 256, 0, stream>>>(w2, w2t, DFF, DMODEL);

    gemm1_k<<<NEXP * 32 * 32, 256, 0, stream>>>(xb, w1t, b1, cnt, off, rows_tok, hbuf);
    gemm2_k<<<NEXP * 32 * 8 * SPLITK, 256, 0, stream>>>(hbuf, w2t, cnt, off, ybuf);
    combine_k<<<TOKENS, 256, 0, stream>>>(ybuf, g_of, tok_e, tok_w, b2, out);

    aux_k<<<1, 256, 0, stream>>>(probs, out + (size_t)TOKENS * DMODEL);
}